// Round 1
// baseline (2482.672 us; speedup 1.0000x reference)
//
#include <hip/hip_runtime.h>
#include <cstdint>
#include <cstddef>

#define HDIM 1024
#define BDIM 64
#define SDIM 2048
#define TWOH 2048
#define MROWS (BDIM * SDIM)   // 131072
#define KDIM TWOH             // 2048 (GEMM K)
#define NEG_BIG -1.0e10f

typedef __bf16 bf16x8 __attribute__((ext_vector_type(8)));
typedef float f32x4 __attribute__((ext_vector_type(4)));

// async 16B global -> LDS (wave-uniform LDS base + lane*16)
__device__ __forceinline__ void gl2lds16(const void* g, void* l) {
    __builtin_amdgcn_global_load_lds(
        (const __attribute__((address_space(1))) void*)(uintptr_t)g,
        (__attribute__((address_space(3))) void*)(uint32_t)(uintptr_t)l,
        16, 0, 0);
}

// ---------------- dec_f = decoder_hidden @ W_h  (fp32, tiny) ----------------
__global__ void decf_kernel(const float* __restrict__ dh,
                            const float* __restrict__ Wh,
                            float* __restrict__ dec_f) {
    int b = blockIdx.y;
    int k = blockIdx.x * 256 + threadIdx.x;
    const float* dhb = dh + b * HDIM;
    float acc = 0.f;
    for (int h = 0; h < HDIM; ++h) acc = fmaf(dhb[h], Wh[h * HDIM + k], acc);
    dec_f[b * HDIM + k] = acc;
}

// ---------------- W_s [2048][1024] fp32 -> WsT [1024][2048] bf16 ------------
__global__ void wst_kernel(const float* __restrict__ Ws, __bf16* __restrict__ WsT) {
    __shared__ float t[32][33];
    int bx = blockIdx.x, by = blockIdx.y;     // bx: n-tile (32), by: k-tile (64)
    int tx = threadIdx.x, ty = threadIdx.y;   // (32, 8)
#pragma unroll
    for (int i = 0; i < 4; ++i)
        t[ty + i * 8][tx] = Ws[(size_t)(by * 32 + ty + i * 8) * HDIM + bx * 32 + tx];
    __syncthreads();
#pragma unroll
    for (int i = 0; i < 4; ++i)
        WsT[(size_t)(bx * 32 + ty + i * 8) * KDIM + by * 32 + tx] = (__bf16)t[tx][ty + i * 8];
}

// ------- fused GEMM: energy[m] += sum_n v[n]*tanh(dec_f[b][n] + (A@B)[m][n]) -------
// A: encoder_outputs fp32 [MROWS][KDIM]; B: WsT bf16 [HDIM][KDIM] (row = n, contiguous k)
__global__ __launch_bounds__(256, 2)
void energy_gemm(const float* __restrict__ enc,
                 const __bf16* __restrict__ WsT,
                 const float* __restrict__ dec_f,
                 const float* __restrict__ v,
                 float* __restrict__ energy) {
    __shared__ __align__(16) float As[128 * 32];   // 16 KB, XOR-swizzled 16B chunks
    __shared__ __align__(16) __bf16 Bs[128 * 32];  // 8 KB, [n][k] XOR-swizzled

    const int tid  = threadIdx.x;
    const int lane = tid & 63;
    const int wave = tid >> 6;
    const int q    = lane >> 4;    // quad 0..3
    const int l15  = lane & 15;
    const int wm   = wave & 1;     // wave grid 2x2 over 128x128
    const int wn   = wave >> 1;

    const int n0 = blockIdx.x * 128;
    const int m0 = blockIdx.y * 128;

    f32x4 zero = {0.f, 0.f, 0.f, 0.f};
    f32x4 acc[4][4];
#pragma unroll
    for (int i = 0; i < 4; ++i)
#pragma unroll
        for (int j = 0; j < 4; ++j) acc[i][j] = zero;

    const char* encB = (const char*)enc;
    const char* wstB = (const char*)WsT;
    char* AsB = (char*)As;
    char* BsB = (char*)Bs;

    for (int kt = 0; kt < KDIM / 32; ++kt) {
        const int k0 = kt * 32;
        // stage A: 1024 chunks of 16B. LDS pos p=r*8+cl holds global chunk cl^(r&7)
#pragma unroll
        for (int c = 0; c < 4; ++c) {
            int p  = c * 256 + tid;
            int r  = p >> 3;
            int cg = (p & 7) ^ (r & 7);
            const void* g = encB + ((size_t)(m0 + r) * KDIM + (size_t)(k0 + cg * 4)) * 4;
            void* l = AsB + (size_t)(c * 256 + wave * 64) * 16;
            gl2lds16(g, l);
        }
        // stage B: 512 chunks. LDS pos p=n*4+cl holds global chunk cl^(n&3)
#pragma unroll
        for (int c = 0; c < 2; ++c) {
            int p  = c * 256 + tid;
            int n  = p >> 2;
            int cg = (p & 3) ^ (n & 3);
            const void* g = wstB + ((size_t)(n0 + n) * KDIM + (size_t)(k0 + cg * 8)) * 2;
            void* l = BsB + (size_t)(c * 256 + wave * 64) * 16;
            gl2lds16(g, l);
        }
        __syncthreads();

        bf16x8 afrag[4];
        const float4* As4 = (const float4*)As;
#pragma unroll
        for (int i = 0; i < 4; ++i) {
            int r  = wm * 64 + i * 16 + l15;
            int p0 = r * 8 + ((2 * q) ^ (r & 7));
            int p1 = r * 8 + ((2 * q + 1) ^ (r & 7));
            float4 f0 = As4[p0];
            float4 f1 = As4[p1];
            bf16x8 a;
            a[0] = (__bf16)f0.x; a[1] = (__bf16)f0.y; a[2] = (__bf16)f0.z; a[3] = (__bf16)f0.w;
            a[4] = (__bf16)f1.x; a[5] = (__bf16)f1.y; a[6] = (__bf16)f1.z; a[7] = (__bf16)f1.w;
            afrag[i] = a;
        }
        bf16x8 bfrag[4];
#pragma unroll
        for (int j = 0; j < 4; ++j) {
            int n = wn * 64 + j * 16 + l15;
            int p = n * 4 + (q ^ (n & 3));
            bfrag[j] = ((const bf16x8*)Bs)[p];
        }
#pragma unroll
        for (int i = 0; i < 4; ++i)
#pragma unroll
            for (int j = 0; j < 4; ++j)
                acc[i][j] = __builtin_amdgcn_mfma_f32_16x16x32_bf16(afrag[i], bfrag[j], acc[i][j], 0, 0, 0);
        __syncthreads();
    }

    // epilogue: per-row partial energy over this tile's 128 columns
    const int b = m0 >> 11;  // 16 m-tiles per batch row; tiles never cross b
    const float* decb = dec_f + b * HDIM;
#pragma unroll
    for (int i = 0; i < 4; ++i) {
        float es0 = 0.f, es1 = 0.f, es2 = 0.f, es3 = 0.f;
#pragma unroll
        for (int j = 0; j < 4; ++j) {
            int col = n0 + wn * 64 + j * 16 + l15;
            float vc = v[col];
            float dc = decb[col];
            f32x4 a = acc[i][j];
            es0 += vc * tanhf(dc + a[0]);
            es1 += vc * tanhf(dc + a[1]);
            es2 += vc * tanhf(dc + a[2]);
            es3 += vc * tanhf(dc + a[3]);
        }
#pragma unroll
        for (int msk = 1; msk <= 8; msk <<= 1) {   // reduce over 16 cols (lanes l15)
            es0 += __shfl_xor(es0, msk);
            es1 += __shfl_xor(es1, msk);
            es2 += __shfl_xor(es2, msk);
            es3 += __shfl_xor(es3, msk);
        }
        if (l15 == 0) {
            int rowbase = m0 + wm * 64 + i * 16 + q * 4;  // C row = quad*4 + reg
            atomicAdd(&energy[rowbase + 0], es0);
            atomicAdd(&energy[rowbase + 1], es1);
            atomicAdd(&energy[rowbase + 2], es2);
            atomicAdd(&energy[rowbase + 3], es3);
        }
    }
}

// ---------------- masked softmax over S, in-place energy -> attn ----------------
__global__ void softmax_kernel(const float* __restrict__ energy,
                               const int* __restrict__ mask,
                               float* __restrict__ attn) {
    int b = blockIdx.x, tx = threadIdx.x;
    const float* eb = energy + b * SDIM;
    const int* mb = mask + b * SDIM;
    float e[8];
    float mx = -3.0e38f;
#pragma unroll
    for (int i = 0; i < 8; ++i) {
        int s = i * 256 + tx;
        float val = (mb[s] != 0) ? eb[s] : NEG_BIG;
        e[i] = val;
        mx = fmaxf(mx, val);
    }
#pragma unroll
    for (int m = 1; m <= 32; m <<= 1) mx = fmaxf(mx, __shfl_xor(mx, m));
    __shared__ float red[4];
    __shared__ float red2[4];
    int wave = tx >> 6, lane = tx & 63;
    if (lane == 0) red[wave] = mx;
    __syncthreads();
    mx = fmaxf(fmaxf(red[0], red[1]), fmaxf(red[2], red[3]));
    float sm = 0.f;
#pragma unroll
    for (int i = 0; i < 8; ++i) { e[i] = expf(e[i] - mx); sm += e[i]; }
#pragma unroll
    for (int m = 1; m <= 32; m <<= 1) sm += __shfl_xor(sm, m);
    if (lane == 0) red2[wave] = sm;
    __syncthreads();
    sm = red2[0] + red2[1] + red2[2] + red2[3];
    float inv = 1.f / sm;
#pragma unroll
    for (int i = 0; i < 8; ++i) attn[b * SDIM + i * 256 + tx] = e[i] * inv;
}

// ---------------- context[b] = sum_s attn[b,s] * enc[b,s,:] ----------------
__global__ void context_kernel(const float* __restrict__ enc,
                               const float* __restrict__ attn,
                               float* __restrict__ ctx) {
    int b = blockIdx.x;
    int col = blockIdx.y * 1024 + threadIdx.x * 4;
    int s0 = blockIdx.z * 512;
    const float* encb = enc + (size_t)b * SDIM * TWOH;
    const float* ab = attn + b * SDIM;
    float a0 = 0.f, a1 = 0.f, a2 = 0.f, a3 = 0.f;
    for (int s = s0; s < s0 + 512; ++s) {
        float w = ab[s];
        if (w != 0.f) {   // masked positions are exactly 0 -> skip (uniform branch)
            const float4 x = *(const float4*)(encb + (size_t)s * TWOH + col);
            a0 += w * x.x; a1 += w * x.y; a2 += w * x.z; a3 += w * x.w;
        }
    }
    float* c = ctx + b * TWOH + col;
    atomicAdd(c + 0, a0);
    atomicAdd(c + 1, a1);
    atomicAdd(c + 2, a2);
    atomicAdd(c + 3, a3);
}

extern "C" void kernel_launch(void* const* d_in, const int* in_sizes, int n_in,
                              void* d_out, int out_size, void* d_ws, size_t ws_size,
                              hipStream_t stream) {
    (void)in_sizes; (void)n_in; (void)out_size; (void)ws_size;
    const float* dh  = (const float*)d_in[0];
    const float* enc = (const float*)d_in[1];
    const int*  mask = (const int*)d_in[2];
    const float* Wh  = (const float*)d_in[3];
    const float* Ws  = (const float*)d_in[4];
    const float* v   = (const float*)d_in[5];

    float* ctx_out  = (float*)d_out;                   // [B][2H]
    float* attn_out = (float*)d_out + BDIM * TWOH;     // [B][S]; doubles as energy buffer

    // workspace: dec_f (256 KB) + WsT bf16 (4 MB)
    float* dec_f = (float*)d_ws;
    __bf16* WsT  = (__bf16*)((char*)d_ws + 262144);

    float* energy = attn_out;  // softmax reads energy then overwrites same slots (same-thread)

    hipMemsetAsync(energy, 0, MROWS * sizeof(float), stream);
    hipMemsetAsync(ctx_out, 0, BDIM * TWOH * sizeof(float), stream);

    decf_kernel<<<dim3(HDIM / 256, BDIM), 256, 0, stream>>>(dh, Wh, dec_f);
    wst_kernel<<<dim3(HDIM / 32, KDIM / 32), dim3(32, 8), 0, stream>>>(Ws, WsT);
    energy_gemm<<<dim3(HDIM / 128, MROWS / 128), 256, 0, stream>>>(enc, WsT, dec_f, v, energy);
    softmax_kernel<<<BDIM, 256, 0, stream>>>(energy, mask, attn_out);
    context_kernel<<<dim3(BDIM, 2, 4), 256, 0, stream>>>(enc, attn_out, ctx_out);
}